// Round 10
// baseline (262.215 us; speedup 1.0000x reference)
//
#include <hip/hip_runtime.h>

// D = H = W = 128, NUM_STEPS = 7 (MONAI DVF2DDF scaling-and-squaring)
#define DD 128
constexpr int NV = DD * DD * DD;          // 2,097,152 voxels
constexpr float INV_SCALE = 1.0f / 128.0f; // 2^-NUM_STEPS
#define NXCD 8

// consistent bijective block swizzle (perf-neutral, measured r4; kept)
__device__ __forceinline__ int swz(int b, int cpx) {
    return (b & (NXCD - 1)) * cpx + (b >> 3);
}

__device__ __forceinline__ void unpack_zyx(int tid, int& z, int& y, int& x) {
    x = tid & (DD - 1);
    y = (tid >> 7) & (DD - 1);
    z = tid >> 14;
}

__device__ __forceinline__ float clampd(float v) {
    return fminf(fmaxf(v, 0.0f), (float)(DD - 1));
}

// ---------------------------------------------------------------------------
// trilinear sample of interleaved 3-channel field (EXACT round-0 expression
// order — verified bit-stable, absmax 0.00390625)
// ---------------------------------------------------------------------------
__device__ __forceinline__ void trilerp3(const float* __restrict__ src,
                                         float cz, float cy, float cx,
                                         float& r0, float& r1, float& r2) {
    float z0f = floorf(cz), y0f = floorf(cy), x0f = floorf(cx);
    float wz = cz - z0f, wy = cy - y0f, wx = cx - x0f;
    int z0 = (int)z0f, y0 = (int)y0f, x0 = (int)x0f;
    int z1 = min(z0 + 1, DD - 1);
    int y1 = min(y0 + 1, DD - 1);
    int x1 = min(x0 + 1, DD - 1);
    float omz = 1.0f - wz, omy = 1.0f - wy, omx = 1.0f - wx;

    int zs0 = z0 << 14, zs1 = z1 << 14;
    int ys0 = y0 << 7,  ys1 = y1 << 7;

    const float* p000 = src + 3 * (zs0 + ys0 + x0);
    const float* p001 = src + 3 * (zs0 + ys0 + x1);
    const float* p010 = src + 3 * (zs0 + ys1 + x0);
    const float* p011 = src + 3 * (zs0 + ys1 + x1);
    const float* p100 = src + 3 * (zs1 + ys0 + x0);
    const float* p101 = src + 3 * (zs1 + ys0 + x1);
    const float* p110 = src + 3 * (zs1 + ys1 + x0);
    const float* p111 = src + 3 * (zs1 + ys1 + x1);

    float w000 = omz * omy * omx, w001 = omz * omy * wx;
    float w010 = omz * wy * omx,  w011 = omz * wy * wx;
    float w100 = wz * omy * omx,  w101 = wz * omy * wx;
    float w110 = wz * wy * omx,   w111 = wz * wy * wx;

    r0 = w000 * p000[0] + w001 * p001[0] + w010 * p010[0] + w011 * p011[0]
       + w100 * p100[0] + w101 * p101[0] + w110 * p110[0] + w111 * p111[0];
    r1 = w000 * p000[1] + w001 * p001[1] + w010 * p010[1] + w011 * p011[1]
       + w100 * p100[1] + w101 * p101[1] + w110 * p110[1] + w111 * p111[1];
    r2 = w000 * p000[2] + w001 * p001[2] + w010 * p010[2] + w011 * p011[2]
       + w100 * p100[2] + w101 * p101[2] + w110 * p110[2] + w111 * p111[2];
}

// bilinear warp of a 1-channel planar volume (exact round-0 expression order)
__device__ __forceinline__ float trilerp1(const float* __restrict__ vol,
                                          float cz, float cy, float cx) {
    float z0f = floorf(cz), y0f = floorf(cy), x0f = floorf(cx);
    float wz = cz - z0f, wy = cy - y0f, wx = cx - x0f;
    int z0 = (int)z0f, y0 = (int)y0f, x0 = (int)x0f;
    int z1 = min(z0 + 1, DD - 1);
    int y1 = min(y0 + 1, DD - 1);
    int x1 = min(x0 + 1, DD - 1);
    float omz = 1.0f - wz, omy = 1.0f - wy, omx = 1.0f - wx;
    int zs0 = z0 << 14, zs1 = z1 << 14;
    int ys0 = y0 << 7,  ys1 = y1 << 7;
    return omz * omy * omx * vol[zs0 + ys0 + x0]
         + omz * omy * wx  * vol[zs0 + ys0 + x1]
         + omz * wy * omx  * vol[zs0 + ys1 + x0]
         + omz * wy * wx   * vol[zs0 + ys1 + x1]
         + wz * omy * omx  * vol[zs1 + ys0 + x0]
         + wz * omy * wx   * vol[zs1 + ys0 + x1]
         + wz * wy * omx   * vol[zs1 + ys1 + x0]
         + wz * wy * wx    * vol[zs1 + ys1 + x1];
}

// corner index computation (same int math as trilerp3)
__device__ __forceinline__ void corner_idx(float cz, float cy, float cx,
                                           int (&idx)[8],
                                           float& wz, float& wy, float& wx) {
    float z0f = floorf(cz), y0f = floorf(cy), x0f = floorf(cx);
    wz = cz - z0f; wy = cy - y0f; wx = cx - x0f;
    int z0 = (int)z0f, y0 = (int)y0f, x0 = (int)x0f;
    int z1 = min(z0 + 1, DD - 1);
    int y1 = min(y0 + 1, DD - 1);
    int x1 = min(x0 + 1, DD - 1);
    int zs0 = z0 << 14, zs1 = z1 << 14;
    int ys0 = y0 << 7,  ys1 = y1 << 7;
    idx[0] = zs0 + ys0 + x0;  idx[1] = zs0 + ys0 + x1;
    idx[2] = zs0 + ys1 + x0;  idx[3] = zs0 + ys1 + x1;
    idx[4] = zs1 + ys0 + x0;  idx[5] = zs1 + ys0 + x1;
    idx[6] = zs1 + ys1 + x0;  idx[7] = zs1 + ys1 + x1;
}

// weighted sum in the EXACT verified order, from pre-loaded corner registers
__device__ __forceinline__ void wsum(const float (&c)[8][3],
                                     float wz, float wy, float wx,
                                     float& r0, float& r1, float& r2) {
    float omz = 1.0f - wz, omy = 1.0f - wy, omx = 1.0f - wx;
    float w000 = omz * omy * omx, w001 = omz * omy * wx;
    float w010 = omz * wy * omx,  w011 = omz * wy * wx;
    float w100 = wz * omy * omx,  w101 = wz * omy * wx;
    float w110 = wz * wy * omx,   w111 = wz * wy * wx;
    r0 = w000 * c[0][0] + w001 * c[1][0] + w010 * c[2][0] + w011 * c[3][0]
       + w100 * c[4][0] + w101 * c[5][0] + w110 * c[6][0] + w111 * c[7][0];
    r1 = w000 * c[0][1] + w001 * c[1][1] + w010 * c[2][1] + w011 * c[3][1]
       + w100 * c[4][1] + w101 * c[5][1] + w110 * c[6][1] + w111 * c[7][1];
    r2 = w000 * c[0][2] + w001 * c[1][2] + w010 * c[2][2] + w011 * c[3][2]
       + w100 * c[4][2] + w101 * c[5][2] + w110 * c[6][2] + w111 * c[7][2];
}

// ===========================================================================
// MAIN PATH: 7 dispatches.
//   1: init+step1 fused (r7-verified, ~44 µs)
//   2-6: MLP step: 2 voxels/thread, all 16 corner loads into two named
//        simultaneously-live register arrays before any weight math.
//        (no sched_barrier — removed after 2x container failures; the
//        VGPR_Count observable tells us whether the cluster survived)
//   7: step7 + final warps fused (r4/r7-verified, ~42 µs)
// ===========================================================================

__global__ __launch_bounds__(256)
void init_step1_kernel(const float* __restrict__ dvf,
                       float* __restrict__ dst,
                       float* __restrict__ dvf_out) {
    int vbid = swz(blockIdx.x, 8192 / NXCD);
    int tid = vbid * 256 + threadIdx.x;
    int z, y, x;
    unpack_zyx(tid, z, y, x);

    float v0 = dvf[tid];
    float v1 = dvf[tid + NV];
    float v2 = dvf[tid + 2 * NV];

    dvf_out[tid]          = v0;
    dvf_out[tid + NV]     = v1;
    dvf_out[tid + 2 * NV] = v2;

    float d0 = v0 * INV_SCALE, d1 = v1 * INV_SCALE, d2 = v2 * INV_SCALE;

    float cz = clampd((float)z + d0);
    float cy = clampd((float)y + d1);
    float cx = clampd((float)x + d2);

    int idx[8];
    float wz, wy, wx;
    corner_idx(cz, cy, cx, idx, wz, wy, wx);
    float omz = 1.0f - wz, omy = 1.0f - wy, omx = 1.0f - wx;
    float w000 = omz * omy * omx, w001 = omz * omy * wx;
    float w010 = omz * wy * omx,  w011 = omz * wy * wx;
    float w100 = wz * omy * omx,  w101 = wz * omy * wx;
    float w110 = wz * wy * omx,   w111 = wz * wy * wx;

    const float* ch0 = dvf;
    const float* ch1 = dvf + NV;
    const float* ch2 = dvf + 2 * NV;

    float t0 = w000 * ch0[idx[0]] + w001 * ch0[idx[1]]
             + w010 * ch0[idx[2]] + w011 * ch0[idx[3]]
             + w100 * ch0[idx[4]] + w101 * ch0[idx[5]]
             + w110 * ch0[idx[6]] + w111 * ch0[idx[7]];
    float t1 = w000 * ch1[idx[0]] + w001 * ch1[idx[1]]
             + w010 * ch1[idx[2]] + w011 * ch1[idx[3]]
             + w100 * ch1[idx[4]] + w101 * ch1[idx[5]]
             + w110 * ch1[idx[6]] + w111 * ch1[idx[7]];
    float t2 = w000 * ch2[idx[0]] + w001 * ch2[idx[1]]
             + w010 * ch2[idx[2]] + w011 * ch2[idx[3]]
             + w100 * ch2[idx[4]] + w101 * ch2[idx[5]]
             + w110 * ch2[idx[6]] + w111 * ch2[idx[7]];

    float* p = dst + 3 * tid;
    p[0] = t0 * INV_SCALE + d0;
    p[1] = t1 * INV_SCALE + d1;
    p[2] = t2 * INV_SCALE + d2;
}

// ---------------------------------------------------------------------------
// MLP squaring step (steps 2..6): 2 voxels/thread (z-halves), all 16 corner
// gathers loaded into two live register arrays before the weight math.
// grid = NV/512 = 4096 blocks
// ---------------------------------------------------------------------------
__global__ __launch_bounds__(256)
void step_mlp_kernel(const float* __restrict__ src, float* __restrict__ dst) {
    int vbid = swz(blockIdx.x, 4096 / NXCD);
    int tidA = vbid * 256 + threadIdx.x;   // z in [0,64)
    int tidB = tidA + NV / 2;              // z in [64,128)

    int zA, yA, xA, zB, yB, xB;
    unpack_zyx(tidA, zA, yA, xA);
    unpack_zyx(tidB, zB, yB, xB);

    const float* sA = src + 3 * tidA;
    const float* sB = src + 3 * tidB;
    float a0 = sA[0], a1 = sA[1], a2 = sA[2];
    float b0 = sB[0], b1 = sB[1], b2 = sB[2];

    float czA = clampd((float)zA + a0);
    float cyA = clampd((float)yA + a1);
    float cxA = clampd((float)xA + a2);
    float czB = clampd((float)zB + b0);
    float cyB = clampd((float)yB + b1);
    float cxB = clampd((float)xB + b2);

    int iA[8], iB[8];
    float wzA, wyA, wxA, wzB, wyB, wxB;
    corner_idx(czA, cyA, cxA, iA, wzA, wyA, wxA);
    corner_idx(czB, cyB, cxB, iB, wzB, wyB, wxB);

    // ---- load cluster: all 16 corner triples into live registers ----
    float cA[8][3], cB[8][3];
    #pragma unroll
    for (int k = 0; k < 8; ++k) {
        const float* p = src + 3 * iA[k];
        cA[k][0] = p[0]; cA[k][1] = p[1]; cA[k][2] = p[2];
    }
    #pragma unroll
    for (int k = 0; k < 8; ++k) {
        const float* p = src + 3 * iB[k];
        cB[k][0] = p[0]; cB[k][1] = p[1]; cB[k][2] = p[2];
    }

    // ---- math cluster (verified expression order) ----
    float rA0, rA1, rA2, rB0, rB1, rB2;
    wsum(cA, wzA, wyA, wxA, rA0, rA1, rA2);
    wsum(cB, wzB, wyB, wxB, rB0, rB1, rB2);

    rA0 += a0; rA1 += a1; rA2 += a2;
    rB0 += b0; rB1 += b1; rB2 += b2;

    float* pA = dst + 3 * tidA;
    float* pB = dst + 3 * tidB;
    pA[0] = rA0; pA[1] = rA1; pA[2] = rA2;
    pB[0] = rB0; pB[1] = rB1; pB[2] = rB2;
}

// ---------------------------------------------------------------------------
// fused step 7 + final (r4/r7-verified)
// ---------------------------------------------------------------------------
__global__ __launch_bounds__(256)
void step7_final_kernel(const float* __restrict__ src,
                        const float* __restrict__ mimg,
                        const float* __restrict__ mlab,
                        float* __restrict__ ddf_out,
                        float* __restrict__ pred_img,
                        float* __restrict__ pred_lab) {
    int vbid = swz(blockIdx.x, 8192 / NXCD);
    int tid = vbid * 256 + threadIdx.x;
    int z, y, x;
    unpack_zyx(tid, z, y, x);

    const float* s = src + 3 * tid;
    float d0 = s[0], d1 = s[1], d2 = s[2];

    float cz = clampd((float)z + d0);
    float cy = clampd((float)y + d1);
    float cx = clampd((float)x + d2);

    float r0, r1, r2;
    trilerp3(src, cz, cy, cx, r0, r1, r2);
    r0 += d0; r1 += d1; r2 += d2;

    ddf_out[tid]          = r0;
    ddf_out[tid + NV]     = r1;
    ddf_out[tid + 2 * NV] = r2;

    float fz = clampd((float)z + r0);
    float fy = clampd((float)y + r1);
    float fx = clampd((float)x + r2);

    pred_img[tid] = trilerp1(mimg, fz, fy, fx);

    int zi = (int)rintf(fz), yi = (int)rintf(fy), xi = (int)rintf(fx);
    pred_lab[tid] = mlab[(zi << 14) + (yi << 7) + xi];
}

// ===========================================================================
// FALLBACK PATH (workspace too small): round-0 verified pipeline in d_out
// ===========================================================================

__global__ __launch_bounds__(256)
void init_kernel_fb(const float* __restrict__ dvf, float* __restrict__ A) {
    int tid = blockIdx.x * blockDim.x + threadIdx.x;
    float d0 = dvf[tid] * INV_SCALE;
    float d1 = dvf[tid + NV] * INV_SCALE;
    float d2 = dvf[tid + 2 * NV] * INV_SCALE;
    float* p = A + 3 * tid;
    p[0] = d0; p[1] = d1; p[2] = d2;
}

template <bool PLANAR_OUT>
__global__ __launch_bounds__(256)
void step_kernel_fb(const float* __restrict__ src, float* __restrict__ dst) {
    int tid = blockIdx.x * blockDim.x + threadIdx.x;
    int z, y, x;
    unpack_zyx(tid, z, y, x);
    const float* s = src + 3 * tid;
    float d0 = s[0], d1 = s[1], d2 = s[2];
    float cz = clampd((float)z + d0);
    float cy = clampd((float)y + d1);
    float cx = clampd((float)x + d2);
    float r0, r1, r2;
    trilerp3(src, cz, cy, cx, r0, r1, r2);
    r0 += d0; r1 += d1; r2 += d2;
    if (PLANAR_OUT) {
        dst[tid]          = r0;
        dst[tid + NV]     = r1;
        dst[tid + 2 * NV] = r2;
    } else {
        float* p = dst + 3 * tid;
        p[0] = r0; p[1] = r1; p[2] = r2;
    }
}

__global__ __launch_bounds__(256)
void final_kernel_fb(const float* __restrict__ ddf,
                     const float* __restrict__ mimg,
                     const float* __restrict__ mlab,
                     const float* __restrict__ dvf,
                     float* __restrict__ pred_img,
                     float* __restrict__ pred_lab,
                     float* __restrict__ dvf_out) {
    int tid = blockIdx.x * blockDim.x + threadIdx.x;
    int z, y, x;
    unpack_zyx(tid, z, y, x);
    float d0 = ddf[tid];
    float d1 = ddf[tid + NV];
    float d2 = ddf[tid + 2 * NV];
    float cz = clampd((float)z + d0);
    float cy = clampd((float)y + d1);
    float cx = clampd((float)x + d2);
    pred_img[tid] = trilerp1(mimg, cz, cy, cx);
    int zi = (int)rintf(cz);
    int yi = (int)rintf(cy);
    int xi = (int)rintf(cx);
    pred_lab[tid] = mlab[(zi << 14) + (yi << 7) + xi];
    dvf_out[tid]          = dvf[tid];
    dvf_out[tid + NV]     = dvf[tid + NV];
    dvf_out[tid + 2 * NV] = dvf[tid + 2 * NV];
}

// ===========================================================================

extern "C" void kernel_launch(void* const* d_in, const int* in_sizes, int n_in,
                              void* d_out, int out_size, void* d_ws, size_t ws_size,
                              hipStream_t stream) {
    const float* dvf  = (const float*)d_in[0];
    const float* mimg = (const float*)d_in[1];
    // d_in[2] = fixed_image: unused by the reference outputs
    const float* mlab = (const float*)d_in[3];

    float* out      = (float*)d_out;
    float* ddf_out  = out;              // slot 0: ddf  [3,D,H,W]
    float* pred_img = out + 3 * NV;     // slot 1
    float* pred_lab = out + 4 * NV;     // slot 2
    float* dvf_out  = out + 5 * NV;     // slot 3: dvf pass-through

    dim3 block(256);
    dim3 grid(NV / 256);       // 8192 blocks (init_step1 / step7_final / fb)
    dim3 hgrid(NV / 512);      // 4096 blocks (2-voxel MLP steps)

    size_t need = (size_t)2 * NV * 3 * sizeof(float);  // 48 MiB ping-pong
    if (d_ws != nullptr && ws_size >= need) {
        float* A = (float*)d_ws;          // interleaved 12B
        float* B = A + (size_t)3 * NV;
        // step 1 fused with init + dvf pass-through -> A
        init_step1_kernel<<<grid, block, 0, stream>>>(dvf, A, dvf_out);
        step_mlp_kernel<<<hgrid, block, 0, stream>>>(A, B);  // 2
        step_mlp_kernel<<<hgrid, block, 0, stream>>>(B, A);  // 3
        step_mlp_kernel<<<hgrid, block, 0, stream>>>(A, B);  // 4
        step_mlp_kernel<<<hgrid, block, 0, stream>>>(B, A);  // 5
        step_mlp_kernel<<<hgrid, block, 0, stream>>>(A, B);  // 6
        step7_final_kernel<<<grid, block, 0, stream>>>(B, mimg, mlab,
                                                       ddf_out, pred_img,
                                                       pred_lab);         // 7
    } else {
        // fallback: round-0 verified pipeline (scratch inside d_out)
        float* A = dvf_out;
        float* B = ddf_out;
        init_kernel_fb<<<grid, block, 0, stream>>>(dvf, A);
        step_kernel_fb<false><<<grid, block, 0, stream>>>(A, B);  // 1
        step_kernel_fb<false><<<grid, block, 0, stream>>>(B, A);  // 2
        step_kernel_fb<false><<<grid, block, 0, stream>>>(A, B);  // 3
        step_kernel_fb<false><<<grid, block, 0, stream>>>(B, A);  // 4
        step_kernel_fb<false><<<grid, block, 0, stream>>>(A, B);  // 5
        step_kernel_fb<false><<<grid, block, 0, stream>>>(B, A);  // 6
        step_kernel_fb<true ><<<grid, block, 0, stream>>>(A, B);  // 7
        final_kernel_fb<<<grid, block, 0, stream>>>(B, mimg, mlab, dvf,
                                                    pred_img, pred_lab, dvf_out);
    }
}